// Round 5
// baseline (3021.407 us; speedup 1.0000x reference)
//
#include <hip/hip_runtime.h>

// GRU B=64 S=512 I=512 H=1024 — fp32 in/out, bf16 MFMA compute.
// v5 (resubmit; round-4 bench was a broker-level container failure, no data):
// v2 structure + SELF-VALIDATING TAGGED TRANSPORT.
//  - 256 WGs x 256 thr (1/CU); 4 batch-groups x 16 batches x 64 blocks x 16 dims;
//    weights bf16 in VGPRs (144/lane). LDS reduce + gates identical to v2.
//  - transport: h element = u32 word (bf16(h)<<16 | step-tag). Producer: ONE
//    relaxed agent-scope u32 store per element, fire-and-forget (no vmcnt ack,
//    no flag store). Consumer: polls its own A-fragment words (32 u64 agent
//    loads/lane) until all low-16 tags == t -> data already in registers.
//    Collapses the v2 4-round-trip chain (store-ack, flag store, flag poll,
//    h load) into 2 (store, poll-with-data).
//  - race-free with depth-2 ping-pong: word for tag t is next overwritten with
//    tag t+2, whose producer first consumed tag-t+1 words that are only
//    published AFTER every group block (incl. this consumer) read tag t.
//  - tags (1..511) never collide with the 0xAA..AA ws poison -> no memset, and
//    '==' tag compare cannot false-positive.
// ws: [0,512KB) u32 tagged h ping-pong [2][B][H].

#define B_ 64
#define S_ 512
#define I_ 512
#define H_ 1024

typedef short short8 __attribute__((ext_vector_type(8)));
typedef float f32x4 __attribute__((ext_vector_type(4)));
typedef unsigned uint4_ __attribute__((ext_vector_type(4)));

__device__ __forceinline__ unsigned short f2bf(float f) {
    unsigned u = __builtin_bit_cast(unsigned, f);
    u += 0x7fffu + ((u >> 16) & 1u);
    return (unsigned short)(u >> 16);
}
__device__ __forceinline__ float sigm(float x) { return 1.f / (1.f + __expf(-x)); }
__device__ __forceinline__ float tanh_(float x) { return 2.f / (1.f + __expf(-2.f * x)) - 1.f; }

__device__ __forceinline__ f32x4 MFMA(short8 a, short8 b, f32x4 c) {
    return __builtin_amdgcn_mfma_f32_16x16x32_bf16(a, b, c, 0, 0, 0);
}

__device__ __forceinline__ short8 cvt8(float4 a, float4 b) {
    short8 r;
    r[0] = (short)f2bf(a.x); r[1] = (short)f2bf(a.y); r[2] = (short)f2bf(a.z); r[3] = (short)f2bf(a.w);
    r[4] = (short)f2bf(b.x); r[5] = (short)f2bf(b.y); r[6] = (short)f2bf(b.z); r[7] = (short)f2bf(b.w);
    return r;
}
__device__ __forceinline__ short8 load8bf(const float* p) {
    return cvt8(*(const float4*)p, *(const float4*)(p + 4));
}

__launch_bounds__(256, 1)
__global__ void gru_persistent(const float* __restrict__ xin,            // [B,S,I] fp32
                               unsigned* htag,                           // ws [2][B][H] u32
                               const float* __restrict__ w_ih,           // [3H,I] fp32
                               const float* __restrict__ w_hh,           // [3H,H] fp32
                               const float* __restrict__ b_ihp,          // [3H] fp32
                               const float* __restrict__ b_hhp,          // [3H] fp32
                               const float* __restrict__ h0,             // [B,H] fp32
                               float* __restrict__ out) {                // fp32 [B,S,H]+[B,H]
    const int tid = threadIdx.x;
    const int w = tid >> 6;        // wave id: K-slice owner
    const int l = tid & 63;
    const int ln = l & 15;         // A-frag: batch row / B-frag: dim col
    const int lq = l >> 4;         // quad -> k sub-offset
    const int grp = blockIdx.x & 3;      // batch group (16 batches)
    const int cu  = blockIdx.x >> 2;     // dim slice  (16 dims)
    const int b0 = grp * 16, d0 = cu * 16;

    // ---- startup: weight B-fragments fp32 -> bf16 -> VGPRs ----
    short8 Whr[8], Whz[8], Whn[8], Wir[4], Wiz[4], Win[4];
    {
        const int nrow = d0 + ln;
        #pragma unroll
        for (int f = 0; f < 8; ++f) {
            int k = w * 256 + f * 32 + lq * 8;
            Whr[f] = load8bf(w_hh + (size_t)(0 * H_ + nrow) * H_ + k);
            Whz[f] = load8bf(w_hh + (size_t)(1 * H_ + nrow) * H_ + k);
            Whn[f] = load8bf(w_hh + (size_t)(2 * H_ + nrow) * H_ + k);
        }
        #pragma unroll
        for (int f = 0; f < 4; ++f) {
            int k = w * 128 + f * 32 + lq * 8;
            Wir[f] = load8bf(w_ih + (size_t)(0 * H_ + nrow) * I_ + k);
            Wiz[f] = load8bf(w_ih + (size_t)(1 * H_ + nrow) * I_ + k);
            Win[f] = load8bf(w_ih + (size_t)(2 * H_ + nrow) * I_ + k);
        }
    }

    // ---- per-thread elementwise assignment: (m_t = batch, n_t = dim) ----
    const int n_t = tid & 15, m_t = tid >> 4;
    const int d = d0 + n_t;
    const float b_r  = b_ihp[d]          + b_hhp[d];
    const float b_z  = b_ihp[H_ + d]     + b_hhp[H_ + d];
    const float b_in = b_ihp[2 * H_ + d];
    const float b_hn = b_hhp[2 * H_ + d];
    float hprev = h0[(size_t)(b0 + m_t) * H_ + d];   // fp32 state in register

    // double-buffered reduction scratch: [parity][gate][wave][n16][m pad20]
    __shared__ float red[2 * 4 * 4 * 16 * 20];

    const int hoff = (b0 + ln) * H_ + w * 256 + lq * 8;          // u32 words
    const float* xrow = xin + (size_t)(b0 + ln) * S_ * I_ + w * 128 + lq * 8;
    unsigned* const hout = htag /* + parity*B_*H_ */ + (size_t)(b0 + m_t) * H_ + d;

    // x prefetch registers (one step ahead)
    float4 xf[8];
    #pragma unroll
    for (int f = 0; f < 4; ++f) {
        xf[2 * f]     = *(const float4*)(xrow + f * 32);
        xf[2 * f + 1] = *(const float4*)(xrow + f * 32 + 4);
    }

    for (int t = 0; t < S_; ++t) {
        // ---- x-gate work first: independent of h, fills the wait window ----
        short8 xA[4];
        #pragma unroll
        for (int f = 0; f < 4; ++f) xA[f] = cvt8(xf[2 * f], xf[2 * f + 1]);

        f32x4 ar = {0,0,0,0}, az = {0,0,0,0}, anh = {0,0,0,0}, anx = {0,0,0,0};
        #pragma unroll
        for (int f = 0; f < 4; ++f) {
            ar  = MFMA(xA[f], Wir[f], ar);
            az  = MFMA(xA[f], Wiz[f], az);
            anx = MFMA(xA[f], Win[f], anx);
        }

        // ---- acquire h: poll own A-fragment tagged words ----
        short8 hA[8];
        if (t == 0) {
            #pragma unroll
            for (int f = 0; f < 8; ++f)
                hA[f] = load8bf(h0 + (size_t)(b0 + ln) * H_ + w * 256 + f * 32 + lq * 8);
        } else {
            const unsigned long long* p =
                (const unsigned long long*)(htag + (size_t)(t & 1) * (B_ * H_) + hoff);
            const unsigned long long MASKT  = 0x0000ffff0000ffffULL;
            const unsigned long long expect = (unsigned long long)(unsigned)t * 0x0000000100000001ULL;
            unsigned long long v[32];
            int guard = 0;
            for (;;) {
                // word q of run kf lives at u64 index kf*16 + (q&3)
                #pragma unroll
                for (int q = 0; q < 32; ++q)
                    v[q] = __hip_atomic_load(p + (q >> 2) * 16 + (q & 3),
                                             __ATOMIC_RELAXED, __HIP_MEMORY_SCOPE_AGENT);
                unsigned long long diff = 0;
                #pragma unroll
                for (int q = 0; q < 32; ++q) diff |= (v[q] ^ expect) & MASKT;
                if (__all((int)(diff == 0ULL))) break;
                if ((++guard & 127) == 0) __builtin_amdgcn_s_sleep(1);
                if (guard > (1 << 18)) break;   // safety valve vs hang
            }
            // strip tags: one v_perm_b32 per output dword
            #pragma unroll
            for (int kf = 0; kf < 8; ++kf) {
                uint4_ o;
                #pragma unroll
                for (int k = 0; k < 4; ++k) {
                    unsigned long long vv = v[kf * 4 + k];
                    o[k] = __builtin_amdgcn_perm((unsigned)(vv >> 32), (unsigned)vv, 0x07060302u);
                }
                hA[kf] = __builtin_bit_cast(short8, o);
            }
        }

        #pragma unroll
        for (int f = 0; f < 8; ++f) {
            ar  = MFMA(hA[f], Whr[f], ar);
            az  = MFMA(hA[f], Whz[f], az);
            anh = MFMA(hA[f], Whn[f], anh);
        }

        // partials -> LDS (parity double-buffered). col(n)=lane&15, row(m)=quad*4+reg
        const int pb = (t & 1) ? 5120 : 0;
        {
            int rbase = pb + (w * 16 + ln) * 20 + lq * 4;
            *(f32x4*)&red[rbase]        = ar;
            *(f32x4*)&red[rbase + 1280] = az;
            *(f32x4*)&red[rbase + 2560] = anh;
            *(f32x4*)&red[rbase + 3840] = anx;
        }
        __syncthreads();   // the ONLY barrier per step

        float rp = 0.f, zp = 0.f, nhp = 0.f, nxp = 0.f;
        #pragma unroll
        for (int ww = 0; ww < 4; ++ww) {
            int ib = pb + (ww * 16 + n_t) * 20 + m_t;
            rp  += red[ib];
            zp  += red[ib + 1280];
            nhp += red[ib + 2560];
            nxp += red[ib + 3840];
        }
        float r = sigm(rp + b_r);
        float z = sigm(zp + b_z);
        float nn = tanh_(nxp + b_in + r * (nhp + b_hn));
        float h = nn + z * (hprev - nn);   // (1-z)*n + z*h
        hprev = h;

        // ---- publish h: ONE tagged u32 store, fire-and-forget ----
        if (t < S_ - 1) {
            unsigned word = ((unsigned)f2bf(h) << 16) | (unsigned)(t + 1);
            __hip_atomic_store(hout + (size_t)((t + 1) & 1) * (B_ * H_),
                               word, __ATOMIC_RELAXED, __HIP_MEMORY_SCOPE_AGENT);
        }

        // ---- off critical path: output store + next-step x prefetch ----
        __builtin_nontemporal_store(h, &out[((size_t)(b0 + m_t) * S_ + t) * H_ + d]);
        if (t == S_ - 1)
            out[(size_t)B_ * S_ * H_ + (size_t)(b0 + m_t) * H_ + d] = h;

        if (t < S_ - 1) {
            const float* xp = xrow + (size_t)(t + 1) * I_;
            #pragma unroll
            for (int f = 0; f < 4; ++f) {
                xf[2 * f]     = *(const float4*)(xp + f * 32);
                xf[2 * f + 1] = *(const float4*)(xp + f * 32 + 4);
            }
        }
    }
}

extern "C" void kernel_launch(void* const* d_in, const int* in_sizes, int n_in,
                              void* d_out, int out_size, void* d_ws, size_t ws_size,
                              hipStream_t stream) {
    const float* xin  = (const float*)d_in[0];   // fp32 [B,S,I]
    const float* h0   = (const float*)d_in[1];   // fp32 [1,B,H]
    const float* w_ih = (const float*)d_in[2];   // fp32 [3H,I]
    const float* w_hh = (const float*)d_in[3];   // fp32 [3H,H]
    const float* b_ih = (const float*)d_in[4];   // fp32 [3H]
    const float* b_hh = (const float*)d_in[5];   // fp32 [3H]
    // size-based disambiguation (w_ih: 3H*I elems, w_hh: 3H*H)
    if (n_in >= 4 && in_sizes[2] == 3 * H_ * H_ && in_sizes[3] == 3 * H_ * I_) {
        const float* tmp = w_ih; w_ih = w_hh; w_hh = tmp;
    }
    float* out = (float*)d_out;
    (void)ws_size;

    // ws: [2][B][H] u32 tagged h ping-pong (512KB). No init needed: the 0xAA
    // poison's low-16 (0xAAAA) never equals a valid tag (1..511).
    unsigned* htag = (unsigned*)d_ws;

    hipLaunchKernelGGL(gru_persistent, dim3(256), dim3(256), 0, stream,
                       xin, htag, w_ih, w_hh, b_ih, b_hh, h0, out);
}